// Round 1
// baseline (278.039 us; speedup 1.0000x reference)
//
#include <hip/hip_runtime.h>
#include <stdint.h>

#define D_MODEL 1024
#define NH 16
#define DK 64
#define BATCH 2
#define SEQ 2048
#define MROWS (BATCH*SEQ)   // 4096

typedef float f32x4 __attribute__((ext_vector_type(4)));
typedef __bf16 bf16x8 __attribute__((ext_vector_type(8)));

#define AS1 __attribute__((address_space(1)))
#define AS3 __attribute__((address_space(3)))

// async global->LDS, 16B per lane, dest = wave-uniform base + lane*16
static __device__ __forceinline__ void gld_lds16(const void* g, void* l) {
    __builtin_amdgcn_global_load_lds((const AS1 unsigned int*)g,
                                     (AS3 unsigned int*)l, 16, 0, 0);
}

// fp32 -> bf16 RNE (no NaNs in this problem)
static __device__ __forceinline__ unsigned int f2bf(float f) {
    union { float f; unsigned int u; } v; v.f = f;
    return (v.u + 0x7fffu + ((v.u >> 16) & 1u)) >> 16;
}

// ---------------------------------------------------------------- prep ----
struct PrepArgs {
    const float* src[7];
    unsigned short* dst[7];
    int n4[7];
};

__global__ __launch_bounds__(256) void prep_cvt(PrepArgs a) {
    const int z = blockIdx.y;
    const float4* s = (const float4*)a.src[z];
    ushort4* d = (ushort4*)a.dst[z];
    const int n = a.n4[z];
    for (int i = blockIdx.x * blockDim.x + threadIdx.x; i < n;
         i += gridDim.x * blockDim.x) {
        float4 v = s[i];
        ushort4 o;
        o.x = (unsigned short)f2bf(v.x);
        o.y = (unsigned short)f2bf(v.y);
        o.z = (unsigned short)f2bf(v.z);
        o.w = (unsigned short)f2bf(v.w);
        d[i] = o;
    }
}

// ---------------------------------------------------------------- GEMM ----
// C[m,n] = (sum_k A[m,k]*W[n,k] + bias[n]) * scale
// A: MxK bf16 row-major, W: NxK bf16 row-major (i.e. B^T layout), K=N=1024.
// 128x128 tile, BK=64, 4 waves (each 64x64), global_load_lds staging with
// XOR swizzle (byte ^= (row&7)<<4) applied on the GLOBAL source (G21) so the
// ds_read_b128 fragment reads are bank-conflict-free.
struct GemmArgs {
    const unsigned short* A[3];
    const unsigned short* W[3];
    const float* bias[3];
    void* C[3];
    float scale[3];
};

template<bool OUT_F32>
__global__ __launch_bounds__(256) void gemm_bt(GemmArgs g) {
    __shared__ unsigned short As[128 * 64];
    __shared__ unsigned short Bs[128 * 64];
    const int z = blockIdx.z;
    const char* A = (const char*)g.A[z];
    const char* W = (const char*)g.W[z];
    const float* bias = g.bias[z];
    const float scale = g.scale[z];
    const int t = threadIdx.x;
    const int w = t >> 6, lane = t & 63;
    const int m0 = blockIdx.x * 128, n0 = blockIdx.y * 128;
    const int wm = (w >> 1) * 64, wn = (w & 1) * 64;

    // staging: thread t covers LDS row srow(+32p), 16B chunk (t&7); source
    // column pre-swizzled so LDS[r][x] = global[r][x ^ ((r&7)<<4)]
    const int srow = t >> 3;
    const int csw = ((t & 7) * 16) ^ ((srow & 7) << 4);
    const char* pA = A + (size_t)(m0 + srow) * 2048 + csw;
    const char* pW = W + (size_t)(n0 + srow) * 2048 + csw;

    f32x4 acc[4][4];
#pragma unroll
    for (int i = 0; i < 4; ++i)
#pragma unroll
        for (int j = 0; j < 4; ++j)
            acc[i][j] = (f32x4){0.f, 0.f, 0.f, 0.f};

    const int kg16 = (lane >> 4) * 16;      // k-group byte offset in row
    const int swl = (lane & 7) << 4;        // row&7 == lane&7 for frag rows

    for (int kt = 0; kt < 16; ++kt) {
        __syncthreads();
#pragma unroll
        for (int p = 0; p < 4; ++p) {
            gld_lds16(pA + (size_t)p * (32 * 2048), &As[w * 512 + p * 2048]);
            gld_lds16(pW + (size_t)p * (32 * 2048), &Bs[w * 512 + p * 2048]);
        }
        pA += 128; pW += 128;
        __syncthreads();
#pragma unroll
        for (int ks = 0; ks < 2; ++ks) {
            bf16x8 af[4], bfv[4];
#pragma unroll
            for (int i = 0; i < 4; ++i) {
                int ra = wm + i * 16 + (lane & 15);
                af[i] = *(const bf16x8*)((const char*)As + ra * 128 +
                                         ((ks * 64 + kg16) ^ swl));
                int rb = wn + i * 16 + (lane & 15);
                bfv[i] = *(const bf16x8*)((const char*)Bs + rb * 128 +
                                          ((ks * 64 + kg16) ^ swl));
            }
#pragma unroll
            for (int i = 0; i < 4; ++i)
#pragma unroll
                for (int j = 0; j < 4; ++j)
                    acc[i][j] = __builtin_amdgcn_mfma_f32_16x16x32_bf16(
                        af[i], bfv[j], acc[i][j], 0, 0, 0);
        }
    }

    float bj[4];
#pragma unroll
    for (int j = 0; j < 4; ++j) bj[j] = bias[n0 + wn + j * 16 + (lane & 15)];
#pragma unroll
    for (int i = 0; i < 4; ++i)
#pragma unroll
        for (int r = 0; r < 4; ++r) {
            int row = m0 + wm + i * 16 + (lane >> 4) * 4 + r;
#pragma unroll
            for (int j = 0; j < 4; ++j) {
                int col = n0 + wn + j * 16 + (lane & 15);
                float v = (acc[i][j][r] + bj[j]) * scale;
                if (OUT_F32)
                    ((float*)g.C[z])[(size_t)row * 1024 + col] = v;
                else
                    ((unsigned short*)g.C[z])[(size_t)row * 1024 + col] =
                        (unsigned short)f2bf(v);
            }
        }
}

// ----------------------------------------------------------- attention ----
// One block per (q-tile of 128 rows, b, h). 4 waves, each owns 32 q rows.
// Swapped QK^T: S^T[key][q] = mfma(K_frag, Q_frag) so per-q softmax reduce
// is a 4-lane shfl_xor(16/32). P transposed per-wave via private LDS.
__global__ __launch_bounds__(256) void attn_fwd(
    const unsigned short* __restrict__ Qb,
    const unsigned short* __restrict__ Kb,
    const unsigned short* __restrict__ Vb,
    const int* __restrict__ mask,
    unsigned short* __restrict__ Ctx) {
    __shared__ unsigned short Klds[64 * 64];     // [key][d]  swizzled rows
    __shared__ unsigned short Vt[64 * 64];       // [d][key]  swizzled rows
    __shared__ unsigned short Plds[4][32 * 64];  // per-wave [q][key] swizzled

    const int qt = blockIdx.x, bh = blockIdx.y;
    const int b = bh >> 4, h = bh & 15;
    const int t = threadIdx.x, w = t >> 6, lane = t & 63;
    const size_t qrow0 = (size_t)b * SEQ + (size_t)qt * 128;
    const int wq0 = w * 32;
    const int kg16 = (lane >> 4) * 16;
    const int swl = (lane & 7) << 4;

    // hoist Q fragments (Q was pre-scaled by 1/8 in the projection epilogue)
    bf16x8 qf[2][2];
#pragma unroll
    for (int nf = 0; nf < 2; ++nf)
#pragma unroll
        for (int ks = 0; ks < 2; ++ks) {
            size_t row = qrow0 + wq0 + nf * 16 + (lane & 15);
            qf[nf][ks] = *(const bf16x8*)((const char*)Qb + row * 2048 +
                                          h * 128 + ks * 64 + kg16);
        }

    f32x4 cacc[2][4];
#pragma unroll
    for (int i = 0; i < 2; ++i)
#pragma unroll
        for (int j = 0; j < 4; ++j) cacc[i][j] = (f32x4){0.f, 0.f, 0.f, 0.f};
    float mstate[2] = {-3e38f, -3e38f};
    float lstate[2] = {0.f, 0.f};

    const char* Kbase = (const char*)Kb + ((size_t)b * SEQ) * 2048 + h * 128;
    const char* Vbase = (const char*)Vb + ((size_t)b * SEQ) * 2048 + h * 128;
    const int* mbase = mask + b * SEQ;

    const int srow = t >> 3;
    const int csw = ((t & 7) * 16) ^ ((srow & 7) << 4);
    const int k2 = t & 31, dblk = t >> 5;

    for (int kv = 0; kv < SEQ / 64; ++kv) {
        const int kv0 = kv * 64;
        __syncthreads();
        // stage K tile (async DMA, pre-swizzled source)
#pragma unroll
        for (int p = 0; p < 2; ++p)
            gld_lds16(Kbase + (size_t)(kv0 + srow + p * 32) * 2048 + csw,
                      &Klds[w * 512 + p * 2048]);
        // stage V transposed: Vt[d][k], pair (k,k+1) packed per ds_write_b32
        {
            const char* vr = Vbase + (size_t)(kv0 + 2 * k2) * 2048 + dblk * 16;
            uint4 va = *(const uint4*)vr;
            uint4 vb2 = *(const uint4*)(vr + 2048);
#pragma unroll
            for (int j = 0; j < 8; ++j) {
                unsigned int pa =
                    (((const unsigned int*)&va)[j >> 1] >> ((j & 1) * 16)) & 0xffffu;
                unsigned int pb =
                    (((const unsigned int*)&vb2)[j >> 1] >> ((j & 1) * 16)) & 0xffffu;
                int d = dblk * 8 + j;
                *(unsigned int*)((char*)Vt + d * 128 +
                                 ((4 * k2) ^ ((d & 7) << 4))) = pa | (pb << 16);
            }
        }
        __syncthreads();

        // S^T = K . Q^T   (keys = MFMA rows, q = cols)
        f32x4 sacc[4][2];
#pragma unroll
        for (int i = 0; i < 4; ++i)
#pragma unroll
            for (int j = 0; j < 2; ++j) sacc[i][j] = (f32x4){0.f, 0.f, 0.f, 0.f};
#pragma unroll
        for (int ks = 0; ks < 2; ++ks) {
            bf16x8 kf[4];
#pragma unroll
            for (int mf = 0; mf < 4; ++mf) {
                int r = mf * 16 + (lane & 15);
                kf[mf] = *(const bf16x8*)((const char*)Klds + r * 128 +
                                          ((ks * 64 + kg16) ^ swl));
            }
#pragma unroll
            for (int mf = 0; mf < 4; ++mf)
#pragma unroll
                for (int nf = 0; nf < 2; ++nf)
                    sacc[mf][nf] = __builtin_amdgcn_mfma_f32_16x16x32_bf16(
                        kf[mf], qf[nf][ks], sacc[mf][nf], 0, 0, 0);
        }

        // mask (exact semantics: masked score := -1e9)
#pragma unroll
        for (int mf = 0; mf < 4; ++mf) {
            int4 mk = *(const int4*)(mbase + kv0 + mf * 16 + (lane >> 4) * 4);
#pragma unroll
            for (int r = 0; r < 4; ++r) {
                int mv = ((const int*)&mk)[r];
                if (mv == 0) {
#pragma unroll
                    for (int nf = 0; nf < 2; ++nf) sacc[mf][nf][r] = -1e9f;
                }
            }
        }

        // online softmax over keys (per q column); 4-lane butterfly
        float scalef[2];
#pragma unroll
        for (int nf = 0; nf < 2; ++nf) {
            float vm = -3e38f;
#pragma unroll
            for (int mf = 0; mf < 4; ++mf)
#pragma unroll
                for (int r = 0; r < 4; ++r) vm = fmaxf(vm, sacc[mf][nf][r]);
            vm = fmaxf(vm, __shfl_xor(vm, 16));
            vm = fmaxf(vm, __shfl_xor(vm, 32));
            float mnew = fmaxf(mstate[nf], vm);
            float sc = __expf(mstate[nf] - mnew);
            scalef[nf] = sc;
            mstate[nf] = mnew;
            float s = 0.f;
#pragma unroll
            for (int mf = 0; mf < 4; ++mf)
#pragma unroll
                for (int r = 0; r < 4; ++r) {
                    float p = __expf(sacc[mf][nf][r] - mnew);
                    sacc[mf][nf][r] = p;
                    s += p;
                }
            s += __shfl_xor(s, 16);
            s += __shfl_xor(s, 32);
            lstate[nf] = lstate[nf] * sc + s;
        }

        // rescale O accumulator; broadcast softmax-layout scale to acc layout
#pragma unroll
        for (int mq = 0; mq < 2; ++mq)
#pragma unroll
            for (int r = 0; r < 4; ++r) {
                float sc = __shfl(scalef[mq], (lane >> 4) * 4 + r);
#pragma unroll
                for (int nd = 0; nd < 4; ++nd) cacc[mq][nd][r] *= sc;
            }

        // P -> per-wave LDS (bf16, [q][key], swizzled), then PV
        unsigned short* Pw = &Plds[w][0];
#pragma unroll
        for (int nf = 0; nf < 2; ++nf)
#pragma unroll
            for (int mf = 0; mf < 4; ++mf) {
                int q = nf * 16 + (lane & 15);
                int kb = mf * 32 + (lane >> 4) * 8;
                unsigned int p0 = f2bf(sacc[mf][nf][0]) | (f2bf(sacc[mf][nf][1]) << 16);
                unsigned int p1 = f2bf(sacc[mf][nf][2]) | (f2bf(sacc[mf][nf][3]) << 16);
                int sw = (q & 7) << 4;
                *(unsigned int*)((char*)Pw + q * 128 + (kb ^ sw)) = p0;
                *(unsigned int*)((char*)Pw + q * 128 + ((kb + 4) ^ sw)) = p1;
            }

#pragma unroll
        for (int ks = 0; ks < 2; ++ks) {
            bf16x8 pa[2], vf[4];
#pragma unroll
            for (int mq = 0; mq < 2; ++mq) {
                int r = mq * 16 + (lane & 15);
                pa[mq] = *(const bf16x8*)((const char*)Pw + r * 128 +
                                          ((ks * 64 + kg16) ^ swl));
            }
#pragma unroll
            for (int nd = 0; nd < 4; ++nd) {
                int r = nd * 16 + (lane & 15);
                vf[nd] = *(const bf16x8*)((const char*)Vt + r * 128 +
                                          ((ks * 64 + kg16) ^ swl));
            }
#pragma unroll
            for (int mq = 0; mq < 2; ++mq)
#pragma unroll
                for (int nd = 0; nd < 4; ++nd)
                    cacc[mq][nd] = __builtin_amdgcn_mfma_f32_16x16x32_bf16(
                        pa[mq], vf[nd], cacc[mq][nd], 0, 0, 0);
        }
    }

    // finalize: 1/l and store context (bf16)
#pragma unroll
    for (int mq = 0; mq < 2; ++mq)
#pragma unroll
        for (int r = 0; r < 4; ++r) {
            float li = __shfl(lstate[mq], (lane >> 4) * 4 + r);
            float inv = 1.f / li;
            size_t row = qrow0 + wq0 + mq * 16 + (lane >> 4) * 4 + r;
#pragma unroll
            for (int nd = 0; nd < 4; ++nd) {
                int col = h * 64 + nd * 16 + (lane & 15);
                Ctx[row * 1024 + col] = (unsigned short)f2bf(cacc[mq][nd][r] * inv);
            }
        }
}

// -------------------------------------------------------------- launch ----
extern "C" void kernel_launch(void* const* d_in, const int* in_sizes, int n_in,
                              void* d_out, int out_size, void* d_ws, size_t ws_size,
                              hipStream_t stream) {
    const float* q   = (const float*)d_in[0];
    const float* k   = (const float*)d_in[1];
    const float* v   = (const float*)d_in[2];
    const int* mask  = (const int*)d_in[3];
    const float* Wq  = (const float*)d_in[4];
    const float* bq  = (const float*)d_in[5];
    const float* Wk  = (const float*)d_in[6];
    const float* bk  = (const float*)d_in[7];
    const float* Wv  = (const float*)d_in[8];
    const float* bv  = (const float*)d_in[9];
    const float* Wo  = (const float*)d_in[10];
    const float* bo  = (const float*)d_in[11];

    unsigned short* ws = (unsigned short*)d_ws;
    const size_t NX = (size_t)MROWS * D_MODEL;   // 4194304 elems
    const size_t NW = (size_t)D_MODEL * D_MODEL; // 1048576 elems
    unsigned short* Xq  = ws;
    unsigned short* Xk  = Xq + NX;
    unsigned short* Xv  = Xk + NX;
    unsigned short* Wqb = Xv + NX;
    unsigned short* Wkb = Wqb + NW;
    unsigned short* Wvb = Wkb + NW;
    unsigned short* Wob = Wvb + NW;
    unsigned short* Qb  = Wob + NW;
    unsigned short* Kb  = Qb + NX;
    unsigned short* Vb  = Kb + NX;
    unsigned short* Cx  = Vb + NX;   // total 64 MB of ws

    PrepArgs pa;
    pa.src[0] = q;  pa.src[1] = k;  pa.src[2] = v;
    pa.src[3] = Wq; pa.src[4] = Wk; pa.src[5] = Wv; pa.src[6] = Wo;
    pa.dst[0] = Xq;  pa.dst[1] = Xk;  pa.dst[2] = Xv;
    pa.dst[3] = Wqb; pa.dst[4] = Wkb; pa.dst[5] = Wvb; pa.dst[6] = Wob;
    for (int i = 0; i < 3; ++i) pa.n4[i] = (int)(NX / 4);
    for (int i = 3; i < 7; ++i) pa.n4[i] = (int)(NW / 4);
    prep_cvt<<<dim3(256, 7), dim3(256), 0, stream>>>(pa);

    GemmArgs gq;
    gq.A[0] = Xq;  gq.A[1] = Xk;  gq.A[2] = Xv;
    gq.W[0] = Wqb; gq.W[1] = Wkb; gq.W[2] = Wvb;
    gq.bias[0] = bq; gq.bias[1] = bk; gq.bias[2] = bv;
    gq.C[0] = Qb; gq.C[1] = Kb; gq.C[2] = Vb;
    gq.scale[0] = 0.125f; gq.scale[1] = 1.f; gq.scale[2] = 1.f; // 1/sqrt(64) folded into Q
    gemm_bt<false><<<dim3(32, 8, 3), dim3(256), 0, stream>>>(gq);

    attn_fwd<<<dim3(16, 32), dim3(256), 0, stream>>>(Qb, Kb, Vb, mask, Cx);

    GemmArgs go;
    go.A[0] = Cx; go.W[0] = Wob; go.bias[0] = bo; go.C[0] = d_out;
    go.scale[0] = 1.f;
    go.A[1] = go.A[2] = nullptr; go.W[1] = go.W[2] = nullptr;
    go.bias[1] = go.bias[2] = nullptr; go.C[1] = go.C[2] = nullptr;
    go.scale[1] = go.scale[2] = 1.f;
    gemm_bt<true><<<dim3(32, 8, 1), dim3(256), 0, stream>>>(go);
}

// Round 2
// 263.297 us; speedup vs baseline: 1.0560x; 1.0560x over previous
//
#include <hip/hip_runtime.h>
#include <stdint.h>

#define D_MODEL 1024
#define NH 16
#define DK 64
#define BATCH 2
#define SEQ 2048
#define MROWS (BATCH*SEQ)   // 4096

typedef float f32x4 __attribute__((ext_vector_type(4)));
typedef __bf16 bf16x8 __attribute__((ext_vector_type(8)));

#define AS1 __attribute__((address_space(1)))
#define AS3 __attribute__((address_space(3)))

// async global->LDS, 16B per lane, dest = wave-uniform base + lane*16
static __device__ __forceinline__ void gld_lds16(const void* g, void* l) {
    __builtin_amdgcn_global_load_lds((const AS1 unsigned int*)g,
                                     (AS3 unsigned int*)l, 16, 0, 0);
}

// fp32 -> bf16 RNE (no NaNs in this problem)
static __device__ __forceinline__ unsigned int f2bf(float f) {
    union { float f; unsigned int u; } v; v.f = f;
    return (v.u + 0x7fffu + ((v.u >> 16) & 1u)) >> 16;
}

// ---------------------------------------------------------------- prep ----
struct PrepArgs {
    const float* src[7];
    unsigned short* dst[7];
    int n4[7];
};

__global__ __launch_bounds__(256) void prep_cvt(PrepArgs a) {
    const int z = blockIdx.y;
    const float4* s = (const float4*)a.src[z];
    ushort4* d = (ushort4*)a.dst[z];
    const int n = a.n4[z];
    for (int i = blockIdx.x * blockDim.x + threadIdx.x; i < n;
         i += gridDim.x * blockDim.x) {
        float4 v = s[i];
        ushort4 o;
        o.x = (unsigned short)f2bf(v.x);
        o.y = (unsigned short)f2bf(v.y);
        o.z = (unsigned short)f2bf(v.z);
        o.w = (unsigned short)f2bf(v.w);
        d[i] = o;
    }
}

// ---------------------------------------------------------------- GEMM ----
// C[m,n] = (sum_k A[m,k]*W[n,k] + bias[n]) * scale
// A: MxK bf16 row-major, W: NxK bf16 row-major, K=N=1024. 128x128 tile,
// BK=64, 4 waves, global_load_lds staging with source-side XOR swizzle.
// hm[z]: write bf16 head-major [bh][s][64]; else flat [row][1024].
struct GemmArgs {
    const unsigned short* A[3];
    const unsigned short* W[3];
    const float* bias[3];
    void* C[3];
    float scale[3];
    int hm[3];
};

template<bool OUT_F32>
__global__ __launch_bounds__(256) void gemm_bt(GemmArgs g) {
    __shared__ unsigned short As[128 * 64];
    __shared__ unsigned short Bs[128 * 64];
    const int z = blockIdx.z;
    const char* A = (const char*)g.A[z];
    const char* W = (const char*)g.W[z];
    const float* bias = g.bias[z];
    const float scale = g.scale[z];
    const int hm = g.hm[z];
    const int t = threadIdx.x;
    const int w = t >> 6, lane = t & 63;
    const int m0 = blockIdx.x * 128, n0 = blockIdx.y * 128;
    const int wm = (w >> 1) * 64, wn = (w & 1) * 64;

    const int srow = t >> 3;
    const int csw = ((t & 7) * 16) ^ ((srow & 7) << 4);
    const char* pA = A + (size_t)(m0 + srow) * 2048 + csw;
    const char* pW = W + (size_t)(n0 + srow) * 2048 + csw;

    f32x4 acc[4][4];
#pragma unroll
    for (int i = 0; i < 4; ++i)
#pragma unroll
        for (int j = 0; j < 4; ++j)
            acc[i][j] = (f32x4){0.f, 0.f, 0.f, 0.f};

    const int kg16 = (lane >> 4) * 16;
    const int swl = (lane & 7) << 4;

    for (int kt = 0; kt < 16; ++kt) {
        __syncthreads();
#pragma unroll
        for (int p = 0; p < 4; ++p) {
            gld_lds16(pA + (size_t)p * (32 * 2048), &As[w * 512 + p * 2048]);
            gld_lds16(pW + (size_t)p * (32 * 2048), &Bs[w * 512 + p * 2048]);
        }
        pA += 128; pW += 128;
        __syncthreads();
#pragma unroll
        for (int ks = 0; ks < 2; ++ks) {
            bf16x8 af[4], bfv[4];
#pragma unroll
            for (int i = 0; i < 4; ++i) {
                int ra = wm + i * 16 + (lane & 15);
                af[i] = *(const bf16x8*)((const char*)As + ra * 128 +
                                         ((ks * 64 + kg16) ^ swl));
                int rb = wn + i * 16 + (lane & 15);
                bfv[i] = *(const bf16x8*)((const char*)Bs + rb * 128 +
                                          ((ks * 64 + kg16) ^ swl));
            }
            __builtin_amdgcn_s_setprio(1);
#pragma unroll
            for (int i = 0; i < 4; ++i)
#pragma unroll
                for (int j = 0; j < 4; ++j)
                    acc[i][j] = __builtin_amdgcn_mfma_f32_16x16x32_bf16(
                        af[i], bfv[j], acc[i][j], 0, 0, 0);
            __builtin_amdgcn_s_setprio(0);
        }
    }

    float bj[4];
#pragma unroll
    for (int j = 0; j < 4; ++j) bj[j] = bias[n0 + wn + j * 16 + (lane & 15)];
#pragma unroll
    for (int i = 0; i < 4; ++i)
#pragma unroll
        for (int r = 0; r < 4; ++r) {
            int row = m0 + wm + i * 16 + (lane >> 4) * 4 + r;
#pragma unroll
            for (int j = 0; j < 4; ++j) {
                int col = n0 + wn + j * 16 + (lane & 15);
                float v = (acc[i][j][r] + bj[j]) * scale;
                if (OUT_F32) {
                    ((float*)g.C[z])[(size_t)row * 1024 + col] = v;
                } else if (hm) {
                    int bb = row >> 11, ss = row & 2047;
                    int hh = col >> 6, dd = col & 63;
                    ((unsigned short*)g.C[z])
                        [(((size_t)(bb * 16 + hh) * 2048) + ss) * 64 + dd] =
                        (unsigned short)f2bf(v);
                } else {
                    ((unsigned short*)g.C[z])[(size_t)row * 1024 + col] =
                        (unsigned short)f2bf(v);
                }
            }
        }
}

// ----------------------------------------------------- V transpose -------
// Vflat [b][s][h*64+d] -> VtT [bh][d][s]   (bf16). LDS 64x64 tile, pad 66.
__global__ __launch_bounds__(256) void tr_v(
    const unsigned short* __restrict__ Vflat,
    unsigned short* __restrict__ VtT) {
    __shared__ unsigned short T[64 * 66];
    const int bh = blockIdx.y, b = bh >> 4, h = bh & 15;
    const int s0 = blockIdx.x * 64;
    const int t = threadIdx.x, row = t >> 3, ch = t & 7;
#pragma unroll
    for (int p = 0; p < 2; ++p) {
        int r = p * 32 + row;
        const unsigned int* src = (const unsigned int*)(
            Vflat + ((size_t)(b * 2048 + s0 + r) * 1024) + h * 64 + ch * 8);
        unsigned int v0 = src[0], v1 = src[1], v2 = src[2], v3 = src[3];
        unsigned int* dst = (unsigned int*)&T[r * 66 + ch * 8];
        dst[0] = v0; dst[1] = v1; dst[2] = v2; dst[3] = v3;
    }
    __syncthreads();
#pragma unroll
    for (int p = 0; p < 2; ++p) {
        int d = p * 32 + row;
        union { unsigned short u16[8]; uint4 v; } o;
#pragma unroll
        for (int j = 0; j < 8; ++j) o.u16[j] = T[(ch * 8 + j) * 66 + d];
        *(uint4*)(VtT + ((size_t)bh * 64 + d) * 2048 + s0 + ch * 8) = o.v;
    }
}

// ----------------------------------------------------------- attention ----
// Qh/Kh: [bh][s][64] bf16 (Q pre-scaled by 1/8). VtT: [bh][d][s] bf16.
// Block = 128 q rows x (b,h); 4 waves x 32 q. K/V double-buffered in LDS,
// staged with global_load_lds + source XOR swizzle; 2-phase pipeline.
__global__ __launch_bounds__(256) void attn_fwd(
    const unsigned short* __restrict__ Qh,
    const unsigned short* __restrict__ Kh,
    const unsigned short* __restrict__ VtT,
    const int* __restrict__ mask,
    unsigned short* __restrict__ Ctx) {
    __shared__ unsigned short KlA[4096], KlB[4096];
    __shared__ unsigned short VlA[4096], VlB[4096];
    __shared__ unsigned short Plds[4][2048];

    // T1: XCD-aware swizzle (nwg=512, 64 consecutive per XCD)
    const int wg = blockIdx.x + (int)gridDim.x * blockIdx.y;
    const int swzid = (wg & 7) * 64 + (wg >> 3);
    const int qt = swzid & 15, bh = swzid >> 4;
    const int b = bh >> 4, h = bh & 15;

    const int t = threadIdx.x, w = t >> 6, lane = t & 63;
    const int wq0 = w * 32;
    const int kg16 = (lane >> 4) * 16;
    const int swl = (lane & 7) << 4;

    // hoist Q fragments (head-major: row stride 128B)
    const char* Qbase = (const char*)Qh + (size_t)bh * 2048 * 128;
    bf16x8 qf[2][2];
#pragma unroll
    for (int nf = 0; nf < 2; ++nf)
#pragma unroll
        for (int ks = 0; ks < 2; ++ks) {
            int row = qt * 128 + wq0 + nf * 16 + (lane & 15);
            qf[nf][ks] = *(const bf16x8*)(Qbase + (size_t)row * 128 +
                                          ks * 64 + kg16);
        }

    f32x4 cacc[2][4];
#pragma unroll
    for (int i = 0; i < 2; ++i)
#pragma unroll
        for (int j = 0; j < 4; ++j) cacc[i][j] = (f32x4){0.f, 0.f, 0.f, 0.f};
    float mstate[2] = {-3e38f, -3e38f};
    float lstate[2] = {0.f, 0.f};

    const char* Kbyte = (const char*)Kh + (size_t)bh * 2048 * 128;
    const char* Vbyte = (const char*)VtT + (size_t)bh * 64 * 4096;
    const int* mbase = mask + b * SEQ;

    const int srow = t >> 3;
    const int csw = ((t & 7) * 16) ^ ((srow & 7) << 4);
    const size_t srow128 = (size_t)srow * 128;
    const size_t srow4096 = (size_t)srow * 4096;

    auto stage = [&](unsigned short* Kd, unsigned short* Vd, int kv0) {
        const char* ks = Kbyte + (size_t)kv0 * 128;
        gld_lds16(ks + srow128 + csw,               Kd + w * 512);
        gld_lds16(ks + srow128 + 32 * 128 + csw,    Kd + 2048 + w * 512);
        const char* vs = Vbyte + (size_t)kv0 * 2;
        gld_lds16(vs + srow4096 + csw,              Vd + w * 512);
        gld_lds16(vs + srow4096 + 32 * 4096 + csw,  Vd + 2048 + w * 512);
    };

    unsigned short* Pw = &Plds[w][0];

    auto compute = [&](const unsigned short* Kl, const unsigned short* Vl,
                       int kv0) {
        // mask load + wave-uniform fast path
        int4 mk[4]; int allone = 1;
#pragma unroll
        for (int mf = 0; mf < 4; ++mf) {
            mk[mf] = *(const int4*)(mbase + kv0 + mf * 16 + (lane >> 4) * 4);
            allone &= (mk[mf].x != 0) & (mk[mf].y != 0) &
                      (mk[mf].z != 0) & (mk[mf].w != 0);
        }

        // S^T = K . Q^T
        f32x4 sacc[4][2];
#pragma unroll
        for (int i = 0; i < 4; ++i)
#pragma unroll
            for (int j = 0; j < 2; ++j) sacc[i][j] = (f32x4){0.f, 0.f, 0.f, 0.f};
#pragma unroll
        for (int ks = 0; ks < 2; ++ks) {
            bf16x8 kf[4];
#pragma unroll
            for (int mf = 0; mf < 4; ++mf) {
                int r = mf * 16 + (lane & 15);
                kf[mf] = *(const bf16x8*)((const char*)Kl + r * 128 +
                                          ((ks * 64 + kg16) ^ swl));
            }
            __builtin_amdgcn_s_setprio(1);
#pragma unroll
            for (int mf = 0; mf < 4; ++mf)
#pragma unroll
                for (int nf = 0; nf < 2; ++nf)
                    sacc[mf][nf] = __builtin_amdgcn_mfma_f32_16x16x32_bf16(
                        kf[mf], qf[nf][ks], sacc[mf][nf], 0, 0, 0);
            __builtin_amdgcn_s_setprio(0);
        }

        if (!__all(allone)) {
#pragma unroll
            for (int mf = 0; mf < 4; ++mf)
#pragma unroll
                for (int r = 0; r < 4; ++r) {
                    int mv = (&mk[mf].x)[r];
                    if (mv == 0) {
                        sacc[mf][0][r] = -1e9f;
                        sacc[mf][1][r] = -1e9f;
                    }
                }
        }

        // online softmax (per q column), hand-treed reductions
        float scalef[2];
#pragma unroll
        for (int nf = 0; nf < 2; ++nf) {
            float a0 = fmaxf(fmaxf(sacc[0][nf][0], sacc[0][nf][1]),
                             fmaxf(sacc[0][nf][2], sacc[0][nf][3]));
            float a1 = fmaxf(fmaxf(sacc[1][nf][0], sacc[1][nf][1]),
                             fmaxf(sacc[1][nf][2], sacc[1][nf][3]));
            float a2 = fmaxf(fmaxf(sacc[2][nf][0], sacc[2][nf][1]),
                             fmaxf(sacc[2][nf][2], sacc[2][nf][3]));
            float a3 = fmaxf(fmaxf(sacc[3][nf][0], sacc[3][nf][1]),
                             fmaxf(sacc[3][nf][2], sacc[3][nf][3]));
            float vm = fmaxf(fmaxf(a0, a1), fmaxf(a2, a3));
            vm = fmaxf(vm, __shfl_xor(vm, 16));
            vm = fmaxf(vm, __shfl_xor(vm, 32));
            float mnew = fmaxf(mstate[nf], vm);
            float sc = __expf(mstate[nf] - mnew);
            scalef[nf] = sc;
            mstate[nf] = mnew;
            float ps[4];
#pragma unroll
            for (int mf = 0; mf < 4; ++mf) {
                float p0 = __expf(sacc[mf][nf][0] - mnew);
                float p1 = __expf(sacc[mf][nf][1] - mnew);
                float p2 = __expf(sacc[mf][nf][2] - mnew);
                float p3 = __expf(sacc[mf][nf][3] - mnew);
                sacc[mf][nf][0] = p0; sacc[mf][nf][1] = p1;
                sacc[mf][nf][2] = p2; sacc[mf][nf][3] = p3;
                ps[mf] = (p0 + p1) + (p2 + p3);
            }
            float s = (ps[0] + ps[1]) + (ps[2] + ps[3]);
            s += __shfl_xor(s, 16);
            s += __shfl_xor(s, 32);
            lstate[nf] = lstate[nf] * sc + s;
        }

        // rescale O accumulator
#pragma unroll
        for (int mq = 0; mq < 2; ++mq)
#pragma unroll
            for (int r = 0; r < 4; ++r) {
                float sc = __shfl(scalef[mq], (lane >> 4) * 4 + r);
#pragma unroll
                for (int nd = 0; nd < 4; ++nd) cacc[mq][nd][r] *= sc;
            }

        // P -> per-wave LDS (bf16, [q][key], swizzled)
#pragma unroll
        for (int nf = 0; nf < 2; ++nf)
#pragma unroll
            for (int mf = 0; mf < 4; ++mf) {
                int q = nf * 16 + (lane & 15);
                int kb = mf * 32 + (lane >> 4) * 8;
                unsigned int p0 = f2bf(sacc[mf][nf][0]) | (f2bf(sacc[mf][nf][1]) << 16);
                unsigned int p1 = f2bf(sacc[mf][nf][2]) | (f2bf(sacc[mf][nf][3]) << 16);
                int sw = (q & 7) << 4;
                *(unsigned int*)((char*)Pw + q * 128 + (kb ^ sw)) = p0;
                *(unsigned int*)((char*)Pw + q * 128 + ((kb + 4) ^ sw)) = p1;
            }

        // PV
#pragma unroll
        for (int ks = 0; ks < 2; ++ks) {
            bf16x8 pa[2], vf[4];
#pragma unroll
            for (int mq = 0; mq < 2; ++mq) {
                int r = mq * 16 + (lane & 15);
                pa[mq] = *(const bf16x8*)((const char*)Pw + r * 128 +
                                          ((ks * 64 + kg16) ^ swl));
            }
#pragma unroll
            for (int nd = 0; nd < 4; ++nd) {
                int r = nd * 16 + (lane & 15);
                vf[nd] = *(const bf16x8*)((const char*)Vl + r * 128 +
                                          ((ks * 64 + kg16) ^ swl));
            }
            __builtin_amdgcn_s_setprio(1);
#pragma unroll
            for (int mq = 0; mq < 2; ++mq)
#pragma unroll
                for (int nd = 0; nd < 4; ++nd)
                    cacc[mq][nd] = __builtin_amdgcn_mfma_f32_16x16x32_bf16(
                        pa[mq], vf[nd], cacc[mq][nd], 0, 0, 0);
            __builtin_amdgcn_s_setprio(0);
        }
    };

    // 2-phase pipeline, statically double-unrolled (A/B buffers)
    stage(KlA, VlA, 0);
    __syncthreads();
    for (int i = 0; i < 16; ++i) {
        const int kv0 = i * 128;
        if (kv0 + 64 < SEQ) stage(KlB, VlB, kv0 + 64);
        compute(KlA, VlA, kv0);
        __syncthreads();
        if (kv0 + 128 < SEQ) stage(KlA, VlA, kv0 + 128);
        compute(KlB, VlB, kv0 + 64);
        __syncthreads();
    }

    // finalize: 1/l and store context (bf16, flat [row][1024])
#pragma unroll
    for (int mq = 0; mq < 2; ++mq)
#pragma unroll
        for (int r = 0; r < 4; ++r) {
            float li = __shfl(lstate[mq], (lane >> 4) * 4 + r);
            float inv = 1.f / li;
            size_t row = (size_t)b * SEQ + qt * 128 + wq0 + mq * 16 +
                         (lane >> 4) * 4 + r;
#pragma unroll
            for (int nd = 0; nd < 4; ++nd) {
                int col = h * 64 + nd * 16 + (lane & 15);
                Ctx[row * 1024 + col] = (unsigned short)f2bf(cacc[mq][nd][r] * inv);
            }
        }
}

// -------------------------------------------------------------- launch ----
extern "C" void kernel_launch(void* const* d_in, const int* in_sizes, int n_in,
                              void* d_out, int out_size, void* d_ws, size_t ws_size,
                              hipStream_t stream) {
    const float* q   = (const float*)d_in[0];
    const float* k   = (const float*)d_in[1];
    const float* v   = (const float*)d_in[2];
    const int* mask  = (const int*)d_in[3];
    const float* Wq  = (const float*)d_in[4];
    const float* bq  = (const float*)d_in[5];
    const float* Wk  = (const float*)d_in[6];
    const float* bk  = (const float*)d_in[7];
    const float* Wv  = (const float*)d_in[8];
    const float* bv  = (const float*)d_in[9];
    const float* Wo  = (const float*)d_in[10];
    const float* bo  = (const float*)d_in[11];

    unsigned short* ws = (unsigned short*)d_ws;
    const size_t NX = (size_t)MROWS * D_MODEL;   // 4194304 elems
    const size_t NW = (size_t)D_MODEL * D_MODEL; // 1048576 elems
    unsigned short* Xq  = ws;
    unsigned short* Xk  = Xq + NX;
    unsigned short* Xv  = Xk + NX;   // reused as VtT after gemm consumes it
    unsigned short* Wqb = Xv + NX;
    unsigned short* Wkb = Wqb + NW;
    unsigned short* Wvb = Wkb + NW;
    unsigned short* Wob = Wvb + NW;
    unsigned short* Qhd = Wob + NW;
    unsigned short* Khd = Qhd + NX;
    unsigned short* Vfl = Khd + NX;
    unsigned short* Cx  = Vfl + NX;   // total 7*NX + 4*NW = ~67 MB

    PrepArgs pa;
    pa.src[0] = q;  pa.src[1] = k;  pa.src[2] = v;
    pa.src[3] = Wq; pa.src[4] = Wk; pa.src[5] = Wv; pa.src[6] = Wo;
    pa.dst[0] = Xq;  pa.dst[1] = Xk;  pa.dst[2] = Xv;
    pa.dst[3] = Wqb; pa.dst[4] = Wkb; pa.dst[5] = Wvb; pa.dst[6] = Wob;
    for (int i = 0; i < 3; ++i) pa.n4[i] = (int)(NX / 4);
    for (int i = 3; i < 7; ++i) pa.n4[i] = (int)(NW / 4);
    prep_cvt<<<dim3(256, 7), dim3(256), 0, stream>>>(pa);

    GemmArgs gq;
    gq.A[0] = Xq;  gq.A[1] = Xk;  gq.A[2] = Xv;
    gq.W[0] = Wqb; gq.W[1] = Wkb; gq.W[2] = Wvb;
    gq.bias[0] = bq; gq.bias[1] = bk; gq.bias[2] = bv;
    gq.C[0] = Qhd; gq.C[1] = Khd; gq.C[2] = Vfl;
    gq.scale[0] = 0.125f; gq.scale[1] = 1.f; gq.scale[2] = 1.f;
    gq.hm[0] = 1; gq.hm[1] = 1; gq.hm[2] = 0;
    gemm_bt<false><<<dim3(32, 8, 3), dim3(256), 0, stream>>>(gq);

    // Vflat -> VtT (into Xv's buffer; Xv input no longer needed)
    tr_v<<<dim3(32, 32), dim3(256), 0, stream>>>(Vfl, Xv);

    attn_fwd<<<dim3(16, 32), dim3(256), 0, stream>>>(Qhd, Khd, Xv, mask, Cx);

    GemmArgs go;
    go.A[0] = Cx; go.W[0] = Wob; go.bias[0] = bo; go.C[0] = d_out;
    go.scale[0] = 1.f; go.hm[0] = 0;
    go.A[1] = go.A[2] = nullptr; go.W[1] = go.W[2] = nullptr;
    go.bias[1] = go.bias[2] = nullptr; go.C[1] = go.C[2] = nullptr;
    go.scale[1] = go.scale[2] = 1.f; go.hm[1] = go.hm[2] = 0;
    gemm_bt<true><<<dim3(32, 8, 1), dim3(256), 0, stream>>>(go);
}

// Round 3
// 227.797 us; speedup vs baseline: 1.2206x; 1.1558x over previous
//
#include <hip/hip_runtime.h>
#include <stdint.h>

#define D_MODEL 1024
#define NH 16
#define DK 64
#define BATCH 2
#define SEQ 2048
#define MROWS (BATCH*SEQ)   // 4096

typedef float f32x4 __attribute__((ext_vector_type(4)));
typedef __bf16 bf16x8 __attribute__((ext_vector_type(8)));

#define AS1 __attribute__((address_space(1)))
#define AS3 __attribute__((address_space(3)))

#if __has_builtin(__builtin_amdgcn_exp2f)
#define EXP2F(x) __builtin_amdgcn_exp2f(x)
#else
#define EXP2F(x) exp2f(x)
#endif
#if __has_builtin(__builtin_amdgcn_rcpf)
#define RCPF(x) __builtin_amdgcn_rcpf(x)
#else
#define RCPF(x) (1.0f/(x))
#endif

// async global->LDS, 16B per lane, dest = wave-uniform base + lane*16
static __device__ __forceinline__ void gld_lds16(const void* g, void* l) {
    __builtin_amdgcn_global_load_lds((const AS1 unsigned int*)g,
                                     (AS3 unsigned int*)l, 16, 0, 0);
}

// HW f32->bf16 (RNE); compiler pairs adjacent casts into v_cvt_pk_bf16_f32
static __device__ __forceinline__ unsigned short bfbits(float f) {
    return __builtin_bit_cast(unsigned short, (__bf16)f);
}
static __device__ __forceinline__ unsigned int pk2bf(float a, float b) {
    return (unsigned int)bfbits(a) | ((unsigned int)bfbits(b) << 16);
}

// ---------------------------------------------------------------- prep ----
struct PrepArgs {
    const float* src[7];
    unsigned short* dst[7];
    int n4[7];
};

__global__ __launch_bounds__(256) void prep_cvt(PrepArgs a) {
    const int z = blockIdx.y;
    const float4* s = (const float4*)a.src[z];
    uint2* d = (uint2*)a.dst[z];
    const int n = a.n4[z];
    for (int i = blockIdx.x * blockDim.x + threadIdx.x; i < n;
         i += gridDim.x * blockDim.x) {
        float4 v = s[i];
        uint2 o;
        o.x = pk2bf(v.x, v.y);
        o.y = pk2bf(v.z, v.w);
        d[i] = o;
    }
}

// ---------------------------------------------------------------- GEMM ----
// C[m,n] = (sum_k A[m,k]*W[n,k] + bias[n]) * scale
// A: MxK bf16 row-major, W: NxK bf16 row-major, K=1024. 128xBN tile, BK=64,
// 4 waves (2x2, each 64 x BN/2), global_load_lds + source-side XOR swizzle.
// hm: 0 = flat [row][1024]; 1 = head-major [bh][s][64]; 2 = V-transposed
// [bh][d][s] (vectorized ushort4 along s).
struct GemmArgs {
    const unsigned short* A[3];
    const unsigned short* W[3];
    const float* bias[3];
    void* C[3];
    float scale[3];
    int hm[3];
};

template<bool OUT_F32, int BN>
__global__ __launch_bounds__(256) void gemm_bt(GemmArgs g) {
    constexpr int JN = BN / 32;          // 16-col frags per wave
    __shared__ unsigned short As[128 * 64];
    __shared__ unsigned short Bs[BN * 64];
    const int z = blockIdx.z;
    const char* A = (const char*)g.A[z];
    const char* W = (const char*)g.W[z];
    const float* bias = g.bias[z];
    const float scale = g.scale[z];
    const int hm = g.hm[z];
    const int t = threadIdx.x;
    const int w = t >> 6, lane = t & 63;
    const int m0 = blockIdx.x * 128, n0 = blockIdx.y * BN;
    const int wm = (w >> 1) * 64, wn = (w & 1) * (BN / 2);

    const int srow = t >> 3;
    const int csw = ((t & 7) * 16) ^ ((srow & 7) << 4);
    const char* pA = A + (size_t)(m0 + srow) * 2048 + csw;
    const char* pW = W + (size_t)(n0 + srow) * 2048 + csw;

    f32x4 acc[4][JN];
#pragma unroll
    for (int i = 0; i < 4; ++i)
#pragma unroll
        for (int j = 0; j < JN; ++j)
            acc[i][j] = (f32x4){0.f, 0.f, 0.f, 0.f};

    const int kg16 = (lane >> 4) * 16;
    const int swl = (lane & 7) << 4;

    for (int kt = 0; kt < 16; ++kt) {
        __syncthreads();
#pragma unroll
        for (int p = 0; p < 4; ++p)
            gld_lds16(pA + (size_t)p * (32 * 2048), &As[w * 512 + p * 2048]);
#pragma unroll
        for (int p = 0; p < JN; ++p)
            gld_lds16(pW + (size_t)p * (32 * 2048), &Bs[w * 512 + p * 2048]);
        pA += 128; pW += 128;
        __syncthreads();
#pragma unroll
        for (int ks = 0; ks < 2; ++ks) {
            bf16x8 af[4], bfv[JN];
#pragma unroll
            for (int i = 0; i < 4; ++i) {
                int ra = wm + i * 16 + (lane & 15);
                af[i] = *(const bf16x8*)((const char*)As + ra * 128 +
                                         ((ks * 64 + kg16) ^ swl));
            }
#pragma unroll
            for (int j = 0; j < JN; ++j) {
                int rb = wn + j * 16 + (lane & 15);
                bfv[j] = *(const bf16x8*)((const char*)Bs + rb * 128 +
                                          ((ks * 64 + kg16) ^ swl));
            }
            __builtin_amdgcn_s_setprio(1);
#pragma unroll
            for (int i = 0; i < 4; ++i)
#pragma unroll
                for (int j = 0; j < JN; ++j)
                    acc[i][j] = __builtin_amdgcn_mfma_f32_16x16x32_bf16(
                        af[i], bfv[j], acc[i][j], 0, 0, 0);
            __builtin_amdgcn_s_setprio(0);
        }
    }

    float bj[JN];
#pragma unroll
    for (int j = 0; j < JN; ++j) bj[j] = bias[n0 + wn + j * 16 + (lane & 15)];

    if (hm == 2) {
        // V-transpose epilogue: [bh][d][s], 4 s-rows per lane -> ushort4
#pragma unroll
        for (int i = 0; i < 4; ++i) {
            int row0 = m0 + wm + i * 16 + ((lane >> 4) << 2);
            int bb = row0 >> 11, ss0 = row0 & 2047;
#pragma unroll
            for (int j = 0; j < JN; ++j) {
                int col = n0 + wn + j * 16 + (lane & 15);
                int hh = col >> 6, dd = col & 63;
                ushort4 o;
                o.x = bfbits(acc[i][j][0] + bj[j]);
                o.y = bfbits(acc[i][j][1] + bj[j]);
                o.z = bfbits(acc[i][j][2] + bj[j]);
                o.w = bfbits(acc[i][j][3] + bj[j]);
                *(ushort4*)((unsigned short*)g.C[z] +
                            (((size_t)(bb * 16 + hh) * 64 + dd) * 2048 + ss0)) = o;
            }
        }
        return;
    }

#pragma unroll
    for (int i = 0; i < 4; ++i)
#pragma unroll
        for (int r = 0; r < 4; ++r) {
            int row = m0 + wm + i * 16 + (lane >> 4) * 4 + r;
#pragma unroll
            for (int j = 0; j < JN; ++j) {
                int col = n0 + wn + j * 16 + (lane & 15);
                float v = (acc[i][j][r] + bj[j]) * scale;
                if (OUT_F32) {
                    ((float*)g.C[z])[(size_t)row * 1024 + col] = v;
                } else if (hm) {
                    int bb = row >> 11, ss = row & 2047;
                    int hh = col >> 6, dd = col & 63;
                    ((unsigned short*)g.C[z])
                        [(((size_t)(bb * 16 + hh) * 2048) + ss) * 64 + dd] =
                        bfbits(v);
                } else {
                    ((unsigned short*)g.C[z])[(size_t)row * 1024 + col] =
                        bfbits(v);
                }
            }
        }
}

// ----------------------------------------------------------- attention ----
// Qh/Kh: [bh][s][64] bf16 (Q pre-scaled by log2(e)/8 -> softmax in exp2
// domain). VtT: [bh][d][s] bf16. Block = 128 q x (b,h); 4 waves x 32 q.
// K/V double-buffered LDS via global_load_lds + source XOR swizzle.
// l accumulated by MFMA ones-column; defer-max rescale (THR=8, log2 domain).
__global__ __launch_bounds__(256) void attn_fwd(
    const unsigned short* __restrict__ Qh,
    const unsigned short* __restrict__ Kh,
    const unsigned short* __restrict__ VtT,
    const int* __restrict__ mask,
    unsigned short* __restrict__ Ctx) {
    __shared__ unsigned short KlA[4096], KlB[4096];
    __shared__ unsigned short VlA[4096], VlB[4096];
    __shared__ unsigned short Plds[4][2048];
    __shared__ int cfl[4];

    // T1: XCD-aware swizzle (nwg=512, 64 consecutive per XCD)
    const int wg = blockIdx.x + (int)gridDim.x * blockIdx.y;
    const int swzid = (wg & 7) * 64 + (wg >> 3);
    const int qt = swzid & 15, bh = swzid >> 4;
    const int b = bh >> 4, h = bh & 15;

    const int t = threadIdx.x, w = t >> 6, lane = t & 63;
    const int wq0 = w * 32;
    const int g = lane >> 4;
    const int kg16 = g * 16;
    const int swl = (lane & 7) << 4;

    // block-wide mask-clean check (hoists all per-tile mask work)
    const int* mbase = mask + b * SEQ;
    int myclean = 1;
#pragma unroll
    for (int i = 0; i < 2; ++i) {
        int4 m4 = ((const int4*)mbase)[t + i * 256];
        myclean &= (m4.x != 0) & (m4.y != 0) & (m4.z != 0) & (m4.w != 0);
    }
    int wc = __all(myclean);
    if (lane == 0) cfl[w] = wc;

    // hoist Q fragments (head-major: row stride 128B)
    const char* Qbase = (const char*)Qh + (size_t)bh * 2048 * 128;
    bf16x8 qf[2][2];
#pragma unroll
    for (int nf = 0; nf < 2; ++nf)
#pragma unroll
        for (int ks = 0; ks < 2; ++ks) {
            int row = qt * 128 + wq0 + nf * 16 + (lane & 15);
            qf[nf][ks] = *(const bf16x8*)(Qbase + (size_t)row * 128 +
                                          ks * 64 + kg16);
        }

    bf16x8 onesf;
#pragma unroll
    for (int j = 0; j < 8; ++j) onesf[j] = (__bf16)1.0f;

    f32x4 cacc[2][4], lacc[2];
#pragma unroll
    for (int i = 0; i < 2; ++i) {
        lacc[i] = (f32x4){0.f, 0.f, 0.f, 0.f};
#pragma unroll
        for (int j = 0; j < 4; ++j) cacc[i][j] = (f32x4){0.f, 0.f, 0.f, 0.f};
    }
    float mstate[2] = {-3e38f, -3e38f};

    const char* Kbyte = (const char*)Kh + (size_t)bh * 2048 * 128;
    const char* Vbyte = (const char*)VtT + (size_t)bh * 64 * 4096;

    const int srow = t >> 3;
    const int csw = ((t & 7) * 16) ^ ((srow & 7) << 4);
    const size_t srow128 = (size_t)srow * 128;
    const size_t srow4096 = (size_t)srow * 4096;

    auto stage = [&](unsigned short* Kd, unsigned short* Vd, int kv0) {
        const char* ks = Kbyte + (size_t)kv0 * 128;
        gld_lds16(ks + srow128 + csw,               Kd + w * 512);
        gld_lds16(ks + srow128 + 32 * 128 + csw,    Kd + 2048 + w * 512);
        const char* vs = Vbyte + (size_t)kv0 * 2;
        gld_lds16(vs + srow4096 + csw,              Vd + w * 512);
        gld_lds16(vs + srow4096 + 32 * 4096 + csw,  Vd + 2048 + w * 512);
    };

    __syncthreads();   // cfl ready (also covers nothing else yet)
    const int clean = cfl[0] & cfl[1] & cfl[2] & cfl[3];

    unsigned short* Pw = &Plds[w][0];

    auto compute = [&](const unsigned short* Kl, const unsigned short* Vl,
                       int kv0) {
        // S^T = K . Q^T  (keys on MFMA rows, q on cols)
        f32x4 sacc[4][2];
#pragma unroll
        for (int i = 0; i < 4; ++i)
#pragma unroll
            for (int j = 0; j < 2; ++j) sacc[i][j] = (f32x4){0.f, 0.f, 0.f, 0.f};
#pragma unroll
        for (int ks = 0; ks < 2; ++ks) {
            bf16x8 kf[4];
#pragma unroll
            for (int mf = 0; mf < 4; ++mf) {
                int r = mf * 16 + (lane & 15);
                kf[mf] = *(const bf16x8*)((const char*)Kl + r * 128 +
                                          ((ks * 64 + kg16) ^ swl));
            }
            __builtin_amdgcn_s_setprio(1);
#pragma unroll
            for (int mf = 0; mf < 4; ++mf)
#pragma unroll
                for (int nf = 0; nf < 2; ++nf)
                    sacc[mf][nf] = __builtin_amdgcn_mfma_f32_16x16x32_bf16(
                        kf[mf], qf[nf][ks], sacc[mf][nf], 0, 0, 0);
            __builtin_amdgcn_s_setprio(0);
        }

        if (!clean) {
#pragma unroll
            for (int mf = 0; mf < 4; ++mf) {
                int4 mk = *(const int4*)(mbase + kv0 + mf * 16 + g * 4);
#pragma unroll
                for (int r = 0; r < 4; ++r) {
                    if ((&mk.x)[r] == 0) {
                        sacc[mf][0][r] = -1e9f;
                        sacc[mf][1][r] = -1e9f;
                    }
                }
            }
        }

        // per-q max (tree + 2 cross-group shuffles); defer-max rescale
        float vm[2];
#pragma unroll
        for (int nf = 0; nf < 2; ++nf) {
            float a0 = fmaxf(fmaxf(sacc[0][nf][0], sacc[0][nf][1]),
                             fmaxf(sacc[0][nf][2], sacc[0][nf][3]));
            float a1 = fmaxf(fmaxf(sacc[1][nf][0], sacc[1][nf][1]),
                             fmaxf(sacc[1][nf][2], sacc[1][nf][3]));
            float a2 = fmaxf(fmaxf(sacc[2][nf][0], sacc[2][nf][1]),
                             fmaxf(sacc[2][nf][2], sacc[2][nf][3]));
            float a3 = fmaxf(fmaxf(sacc[3][nf][0], sacc[3][nf][1]),
                             fmaxf(sacc[3][nf][2], sacc[3][nf][3]));
            float m4 = fmaxf(fmaxf(a0, a1), fmaxf(a2, a3));
            m4 = fmaxf(m4, __shfl_xor(m4, 16));
            vm[nf] = fmaxf(m4, __shfl_xor(m4, 32));
        }
        if (!__all((vm[0] <= mstate[0] + 8.f) & (vm[1] <= mstate[1] + 8.f))) {
            float sc[2];
#pragma unroll
            for (int nf = 0; nf < 2; ++nf) {
                float mnew = fmaxf(mstate[nf], vm[nf]);
                sc[nf] = EXP2F(mstate[nf] - mnew);
                mstate[nf] = mnew;
            }
#pragma unroll
            for (int mq = 0; mq < 2; ++mq)
#pragma unroll
                for (int r = 0; r < 4; ++r) {
                    float scb = __shfl(sc[mq], g * 4 + r);
                    lacc[mq][r] *= scb;
#pragma unroll
                    for (int nd = 0; nd < 4; ++nd) cacc[mq][nd][r] *= scb;
                }
        }

        // P = 2^(S'-m), pack bf16, write to per-wave LDS (b64, swizzled)
#pragma unroll
        for (int nf = 0; nf < 2; ++nf) {
            float mn = mstate[nf];
#pragma unroll
            for (int mf = 0; mf < 4; ++mf) {
                unsigned int d0 = pk2bf(EXP2F(sacc[mf][nf][0] - mn),
                                        EXP2F(sacc[mf][nf][1] - mn));
                unsigned int d1 = pk2bf(EXP2F(sacc[mf][nf][2] - mn),
                                        EXP2F(sacc[mf][nf][3] - mn));
                int q = nf * 16 + (lane & 15);
                int kb = mf * 32 + g * 8;
                unsigned long long pv =
                    (unsigned long long)d0 | ((unsigned long long)d1 << 32);
                *(unsigned long long*)((char*)Pw + q * 128 +
                                       (kb ^ ((q & 7) << 4))) = pv;
            }
        }

        // PV + l accumulation (ones column)
#pragma unroll
        for (int ks = 0; ks < 2; ++ks) {
            bf16x8 pa[2], vf[4];
#pragma unroll
            for (int mq = 0; mq < 2; ++mq) {
                int r = mq * 16 + (lane & 15);
                pa[mq] = *(const bf16x8*)((const char*)Pw + r * 128 +
                                          ((ks * 64 + kg16) ^ swl));
            }
#pragma unroll
            for (int nd = 0; nd < 4; ++nd) {
                int r = nd * 16 + (lane & 15);
                vf[nd] = *(const bf16x8*)((const char*)Vl + r * 128 +
                                          ((ks * 64 + kg16) ^ swl));
            }
            __builtin_amdgcn_s_setprio(1);
#pragma unroll
            for (int mq = 0; mq < 2; ++mq) {
                lacc[mq] = __builtin_amdgcn_mfma_f32_16x16x32_bf16(
                    pa[mq], onesf, lacc[mq], 0, 0, 0);
#pragma unroll
                for (int nd = 0; nd < 4; ++nd)
                    cacc[mq][nd] = __builtin_amdgcn_mfma_f32_16x16x32_bf16(
                        pa[mq], vf[nd], cacc[mq][nd], 0, 0, 0);
            }
            __builtin_amdgcn_s_setprio(0);
        }
    };

    // 2-phase pipeline, statically double-unrolled (A/B buffers)
    stage(KlA, VlA, 0);
    __syncthreads();
    for (int i = 0; i < 16; ++i) {
        const int kv0 = i * 128;
        if (kv0 + 64 < SEQ) stage(KlB, VlB, kv0 + 64);
        compute(KlA, VlA, kv0);
        __syncthreads();
        if (kv0 + 128 < SEQ) stage(KlA, VlA, kv0 + 128);
        compute(KlB, VlB, kv0 + 64);
        __syncthreads();
    }

    // finalize: 1/l (lacc already in cacc layout) and store context bf16
#pragma unroll
    for (int mq = 0; mq < 2; ++mq)
#pragma unroll
        for (int r = 0; r < 4; ++r) {
            float inv = RCPF(lacc[mq][r]);
            size_t row = (size_t)b * SEQ + qt * 128 + wq0 + mq * 16 +
                         g * 4 + r;
#pragma unroll
            for (int nd = 0; nd < 4; ++nd) {
                int col = h * 64 + nd * 16 + (lane & 15);
                Ctx[row * 1024 + col] = bfbits(cacc[mq][nd][r] * inv);
            }
        }
}

// -------------------------------------------------------------- launch ----
extern "C" void kernel_launch(void* const* d_in, const int* in_sizes, int n_in,
                              void* d_out, int out_size, void* d_ws, size_t ws_size,
                              hipStream_t stream) {
    const float* q   = (const float*)d_in[0];
    const float* k   = (const float*)d_in[1];
    const float* v   = (const float*)d_in[2];
    const int* mask  = (const int*)d_in[3];
    const float* Wq  = (const float*)d_in[4];
    const float* bq  = (const float*)d_in[5];
    const float* Wk  = (const float*)d_in[6];
    const float* bk  = (const float*)d_in[7];
    const float* Wv  = (const float*)d_in[8];
    const float* bv  = (const float*)d_in[9];
    const float* Wo  = (const float*)d_in[10];
    const float* bo  = (const float*)d_in[11];

    unsigned short* ws = (unsigned short*)d_ws;
    const size_t NX = (size_t)MROWS * D_MODEL;   // 4194304 elems
    const size_t NW = (size_t)D_MODEL * D_MODEL; // 1048576 elems
    unsigned short* Xq  = ws;
    unsigned short* Xk  = Xq + NX;
    unsigned short* Xv  = Xk + NX;
    unsigned short* Wqb = Xv + NX;
    unsigned short* Wkb = Wqb + NW;
    unsigned short* Wvb = Wkb + NW;
    unsigned short* Wob = Wvb + NW;
    unsigned short* Qhd = Wob + NW;
    unsigned short* Khd = Qhd + NX;
    unsigned short* Vtt = Khd + NX;
    unsigned short* Cx  = Vtt + NX;

    PrepArgs pa;
    pa.src[0] = q;  pa.src[1] = k;  pa.src[2] = v;
    pa.src[3] = Wq; pa.src[4] = Wk; pa.src[5] = Wv; pa.src[6] = Wo;
    pa.dst[0] = Xq;  pa.dst[1] = Xk;  pa.dst[2] = Xv;
    pa.dst[3] = Wqb; pa.dst[4] = Wkb; pa.dst[5] = Wvb; pa.dst[6] = Wob;
    for (int i = 0; i < 3; ++i) pa.n4[i] = (int)(NX / 4);
    for (int i = 3; i < 7; ++i) pa.n4[i] = (int)(NW / 4);
    prep_cvt<<<dim3(256, 7), dim3(256), 0, stream>>>(pa);

    GemmArgs gq;
    gq.A[0] = Xq;  gq.A[1] = Xk;  gq.A[2] = Xv;
    gq.W[0] = Wqb; gq.W[1] = Wkb; gq.W[2] = Wvb;
    gq.bias[0] = bq; gq.bias[1] = bk; gq.bias[2] = bv;
    gq.C[0] = Qhd; gq.C[1] = Khd; gq.C[2] = Vtt;
    // Q pre-scale: (1/sqrt(64)) * log2(e)  -> softmax runs in exp2 domain
    gq.scale[0] = 0.125f * 1.44269504088896340736f;
    gq.scale[1] = 1.f; gq.scale[2] = 1.f;
    gq.hm[0] = 1; gq.hm[1] = 1; gq.hm[2] = 2;
    gemm_bt<false, 128><<<dim3(32, 8, 3), dim3(256), 0, stream>>>(gq);

    attn_fwd<<<dim3(16, 32), dim3(256), 0, stream>>>(Qhd, Khd, Vtt, mask, Cx);

    GemmArgs go;
    go.A[0] = Cx; go.W[0] = Wob; go.bias[0] = bo; go.C[0] = d_out;
    go.scale[0] = 1.f; go.hm[0] = 0;
    go.A[1] = go.A[2] = nullptr; go.W[1] = go.W[2] = nullptr;
    go.bias[1] = go.bias[2] = nullptr; go.C[1] = go.C[2] = nullptr;
    go.scale[1] = go.scale[2] = 1.f; go.hm[1] = go.hm[2] = 0;
    gemm_bt<true, 64><<<dim3(32, 16, 1), dim3(256), 0, stream>>>(go);
}